// Round 1
// baseline (232.127 us; speedup 1.0000x reference)
//
#include <hip/hip_runtime.h>

#define B_ 16
#define N_ 2048
#define ITILE 32
#define JSPLIT 8
#define JCHUNK (N_ / JSPLIT)   // 256 j-iterations per thread

// Each block: one batch b, one 32-row i-tile. 256 threads = (32 i) x (8 j-chunks).
__global__ __launch_bounds__(256) void bpr_pair_kernel(
    const float* __restrict__ logits,
    const int*   __restrict__ labels,
    float*       __restrict__ s_acc)   // [B][3] level sums
{
    __shared__ float xj_s[N_];
    __shared__ int   lj_s[N_];
    __shared__ float lsum[3];

    const int b     = blockIdx.x / (N_ / ITILE);
    const int itile = blockIdx.x % (N_ / ITILE);
    const int tid   = threadIdx.x;

    // Stage the whole row for this batch into LDS (coalesced).
    const float* xrow = logits + (size_t)b * N_;
    const int*   lrow = labels + (size_t)b * N_;
    for (int k = tid; k < N_; k += 256) {
        xj_s[k] = xrow[k];
        lj_s[k] = lrow[k];
    }
    if (tid < 3) lsum[tid] = 0.0f;
    __syncthreads();

    const int i_local = tid >> 3;   // 0..31
    const int jc      = tid & 7;    // 0..7
    const int i       = itile * ITILE + i_local;
    const float xi    = xj_s[i];
    const int   li    = lj_s[i];

    // Each thread scans j = jc, jc+8, jc+16, ... (stride-8 interleave):
    // per iteration the wave touches 8 consecutive LDS words, each broadcast
    // to 8 lanes -> no bank conflicts.
    float acc = 0.0f;
    #pragma unroll 4
    for (int jj = 0; jj < JCHUNK; ++jj) {
        const int   j  = jj * JSPLIT + jc;
        const float d  = xi - xj_s[j];
        const int   lj = lj_s[j];
        // stable logsigmoid(d) = min(d,0) - log1p(exp(-|d|))
        const float ls = fminf(d, 0.0f) - log1pf(__expf(-fabsf(d)));
        acc += (lj < li) ? ls : 0.0f;
    }

    if (li > 0) atomicAdd(&lsum[li - 1], acc);
    __syncthreads();
    if (tid < 3) atomicAdd(&s_acc[b * 3 + tid], lsum[tid]);
}

__global__ __launch_bounds__(256) void bpr_finalize(
    const int*   __restrict__ labels,
    const float* __restrict__ s_acc,
    float*       __restrict__ out)
{
    __shared__ int hist[B_][4];
    const int tid = threadIdx.x;
    if (tid < B_ * 4) ((int*)hist)[tid] = 0;
    __syncthreads();

    for (int idx = tid; idx < B_ * N_; idx += 256) {
        const int b = idx >> 11;            // N_ == 2048
        atomicAdd(&hist[b][labels[idx]], 1);
    }
    __syncthreads();

    if (tid == 0) {
        float total = 0.0f;
        for (int b = 0; b < B_; ++b) {
            float msum = 0.0f, vsum = 0.0f;
            int below = hist[b][0];                 // count(labels < lvl)
            for (int lvl = 1; lvl < 4; ++lvl) {
                const int pos = hist[b][lvl];
                const long long cnt = (long long)pos * (long long)below;
                if (cnt > 0) {
                    msum += s_acc[b * 3 + (lvl - 1)] / (float)cnt;
                    vsum += 1.0f;
                }
                below += pos;
            }
            total += msum / fmaxf(vsum, 1.0f);
        }
        out[0] = -total / (float)B_;
    }
}

extern "C" void kernel_launch(void* const* d_in, const int* in_sizes, int n_in,
                              void* d_out, int out_size, void* d_ws, size_t ws_size,
                              hipStream_t stream)
{
    const float* logits = (const float*)d_in[0];
    const int*   labels = (const int*)d_in[1];
    float*       out    = (float*)d_out;
    float*       s_acc  = (float*)d_ws;

    // d_ws is poisoned (0xAA) and never re-poisoned between replays: zero the
    // 48 accumulators every launch (async memset is graph-capture safe).
    hipMemsetAsync(s_acc, 0, B_ * 3 * sizeof(float), stream);

    bpr_pair_kernel<<<dim3(B_ * (N_ / ITILE)), 256, 0, stream>>>(logits, labels, s_acc);
    bpr_finalize<<<1, 256, 0, stream>>>(labels, s_acc, out);
}

// Round 3
// 55.866 us; speedup vs baseline: 4.1551x; 4.1551x over previous
//
#include <hip/hip_runtime.h>

#define B_ 16
#define N_ 2048
#define ITILE 32
#define JSPLIT 8
#define JCHUNK (N_ / JSPLIT)   // 256 j-iterations per thread

// HW transcendentals: v_exp_f32 (2^x) and v_log_f32 (log2 x), single instr each.
__device__ __forceinline__ float fast_exp2(float x) { return __builtin_amdgcn_exp2f(x); }
__device__ __forceinline__ float fast_log2(float x) { return __builtin_amdgcn_logf(x); }

// Each block: one batch b, one 32-row i-tile. 256 threads = (32 i) x (8 j-chunks).
__global__ __launch_bounds__(256) void bpr_pair_kernel(
    const float* __restrict__ logits,
    const int*   __restrict__ labels,
    float*       __restrict__ s_acc)   // [B][3] level sums
{
    __shared__ float2 s_pk[N_];   // {logit, (float)label} packed -> one ds_read_b64
    __shared__ float  lsum[3];

    const int b     = blockIdx.x / (N_ / ITILE);
    const int itile = blockIdx.x % (N_ / ITILE);
    const int tid   = threadIdx.x;

    // Stage the whole row for this batch into LDS (coalesced).
    const float* xrow = logits + (size_t)b * N_;
    const int*   lrow = labels + (size_t)b * N_;
    for (int k = tid; k < N_; k += 256) {
        s_pk[k] = make_float2(xrow[k], (float)lrow[k]);
    }
    if (tid < 3) lsum[tid] = 0.0f;
    __syncthreads();

    const int i_local = tid >> 3;   // 0..31
    const int jc      = tid & 7;    // 0..7
    const int i       = itile * ITILE + i_local;
    const float xi  = s_pk[i].x;
    const float lif = s_pk[i].y;
    const int   li  = (int)lif;

    // j = jc, jc+8, jc+16, ... : per iteration the wave touches 8 consecutive
    // float2 slots, each broadcast to 8 lanes -> conflict-free.
    // Fast stable logsigmoid(d) = min(d,0) - ln2 * log2(1 + exp2(-|d|*log2e))
    const float LOG2E = 1.442695040888963f;
    const float LN2   = 0.693147180559945f;
    float acc = 0.0f;
    #pragma unroll 8
    for (int jj = 0; jj < JCHUNK; ++jj) {
        const int    j = jj * JSPLIT + jc;
        const float2 p = s_pk[j];
        const float  d = xi - p.x;
        const float  e = fast_exp2(-fabsf(d) * LOG2E);
        const float ls = fminf(d, 0.0f) - LN2 * fast_log2(1.0f + e);
        acc += (p.y < lif) ? ls : 0.0f;
    }

    if (li > 0) atomicAdd(&lsum[li - 1], acc);
    __syncthreads();
    if (tid < 3) atomicAdd(&s_acc[b * 3 + tid], lsum[tid]);
}

__global__ __launch_bounds__(256) void bpr_finalize(
    const int*   __restrict__ labels,
    const float* __restrict__ s_acc,
    float*       __restrict__ out)
{
    __shared__ int hist[B_][4];
    const int tid = threadIdx.x;
    if (tid < B_ * 4) ((int*)hist)[tid] = 0;
    __syncthreads();

    for (int idx = tid; idx < B_ * N_; idx += 256) {
        const int b = idx >> 11;            // N_ == 2048
        atomicAdd(&hist[b][labels[idx]], 1);
    }
    __syncthreads();

    if (tid == 0) {
        float total = 0.0f;
        for (int b = 0; b < B_; ++b) {
            float msum = 0.0f, vsum = 0.0f;
            int below = hist[b][0];                 // count(labels < lvl)
            for (int lvl = 1; lvl < 4; ++lvl) {
                const int pos = hist[b][lvl];
                const long long cnt = (long long)pos * (long long)below;
                if (cnt > 0) {
                    msum += s_acc[b * 3 + (lvl - 1)] / (float)cnt;
                    vsum += 1.0f;
                }
                below += pos;
            }
            total += msum / fmaxf(vsum, 1.0f);
        }
        out[0] = -total / (float)B_;
    }
}

extern "C" void kernel_launch(void* const* d_in, const int* in_sizes, int n_in,
                              void* d_out, int out_size, void* d_ws, size_t ws_size,
                              hipStream_t stream)
{
    const float* logits = (const float*)d_in[0];
    const int*   labels = (const int*)d_in[1];
    float*       out    = (float*)d_out;
    float*       s_acc  = (float*)d_ws;

    // d_ws is poisoned (0xAA) and never re-poisoned between replays: zero the
    // 48 accumulators every launch (async memset is graph-capture safe).
    (void)hipMemsetAsync(s_acc, 0, B_ * 3 * sizeof(float), stream);

    bpr_pair_kernel<<<dim3(B_ * (N_ / ITILE)), 256, 0, stream>>>(logits, labels, s_acc);
    bpr_finalize<<<1, 256, 0, stream>>>(labels, s_acc, out);
}

// Round 4
// 37.109 us; speedup vs baseline: 6.2553x; 1.5055x over previous
//
#include <hip/hip_runtime.h>

#define B_ 16
#define N_ 2048
#define ITILE 32
#define JSPLIT 8
#define JCHUNK (N_ / JSPLIT)   // 256 j-iterations per thread

// HW transcendentals: v_exp_f32 (2^x) and v_log_f32 (log2 x), single instr each.
__device__ __forceinline__ float fast_exp2(float x) { return __builtin_amdgcn_exp2f(x); }
__device__ __forceinline__ float fast_log2(float x) { return __builtin_amdgcn_logf(x); }

// ws layout: [0..47] float s_acc[B][3] (atomically accumulated, memset to 0)
//            [48..111] int cnt[B][4]   (written whole by itile==0 blocks)

// Each block: one batch b, one 32-row i-tile. 256 threads = (32 i) x (8 j-chunks).
__global__ __launch_bounds__(256) void bpr_pair_kernel(
    const float* __restrict__ logits,
    const int*   __restrict__ labels,
    float*       __restrict__ s_acc,   // [B][3] level sums
    int*         __restrict__ cnt)     // [B][4] label histogram
{
    __shared__ float2 s_pk[N_];   // {logit, (float)label} packed -> one ds_read_b64
    __shared__ float  lsum[3];
    __shared__ int    wsum[8];    // 4 waves x 2 packed histogram fields

    const int b     = blockIdx.x / (N_ / ITILE);
    const int itile = blockIdx.x % (N_ / ITILE);
    const int tid   = threadIdx.x;

    // Stage the whole row for this batch into LDS (coalesced).
    const float* xrow = logits + (size_t)b * N_;
    const int*   lrow = labels + (size_t)b * N_;
    for (int k = tid; k < N_; k += 256) {
        s_pk[k] = make_float2(xrow[k], (float)lrow[k]);
    }
    if (tid < 3) lsum[tid] = 0.0f;
    __syncthreads();

    // One block per batch computes the label histogram from LDS (hidden under
    // the other 63 blocks' pair work). Block-uniform branch -> barrier-safe.
    if (itile == 0) {
        int cA = 0, cB = 0;   // c0 + (c1<<16), c2 + (c3<<16); totals <= 2048 fit 16b
        for (int k = tid; k < N_; k += 256) {
            const int l = (int)s_pk[k].y;
            cA += (l == 0 ? 1 : 0) + (l == 1 ? (1 << 16) : 0);
            cB += (l == 2 ? 1 : 0) + (l == 3 ? (1 << 16) : 0);
        }
        #pragma unroll
        for (int off = 32; off > 0; off >>= 1) {
            cA += __shfl_xor(cA, off);
            cB += __shfl_xor(cB, off);
        }
        if ((tid & 63) == 0) {
            wsum[(tid >> 6) * 2 + 0] = cA;
            wsum[(tid >> 6) * 2 + 1] = cB;
        }
        __syncthreads();
        if (tid == 0) {
            int tA = wsum[0] + wsum[2] + wsum[4] + wsum[6];
            int tB = wsum[1] + wsum[3] + wsum[5] + wsum[7];
            cnt[b * 4 + 0] = tA & 0xFFFF;
            cnt[b * 4 + 1] = tA >> 16;
            cnt[b * 4 + 2] = tB & 0xFFFF;
            cnt[b * 4 + 3] = tB >> 16;
        }
    }

    const int i_local = tid >> 3;   // 0..31
    const int jc      = tid & 7;    // 0..7
    const int i       = itile * ITILE + i_local;
    const float xi  = s_pk[i].x;
    const float lif = s_pk[i].y;
    const int   li  = (int)lif;

    // j = jc, jc+8, jc+16, ... : per iteration the wave touches 8 consecutive
    // float2 slots, each broadcast to 8 lanes -> conflict-free.
    // Fast stable logsigmoid(d) = min(d,0) - ln2 * log2(1 + exp2(-|d|*log2e))
    const float LOG2E = 1.442695040888963f;
    const float LN2   = 0.693147180559945f;
    float acc = 0.0f;
    #pragma unroll 8
    for (int jj = 0; jj < JCHUNK; ++jj) {
        const int    j = jj * JSPLIT + jc;
        const float2 p = s_pk[j];
        const float  d = xi - p.x;
        const float  e = fast_exp2(-fabsf(d) * LOG2E);
        const float ls = fminf(d, 0.0f) - LN2 * fast_log2(1.0f + e);
        acc += (p.y < lif) ? ls : 0.0f;
    }

    if (li > 0) atomicAdd(&lsum[li - 1], acc);
    __syncthreads();
    if (tid < 3) atomicAdd(&s_acc[b * 3 + tid], lsum[tid]);
}

// One wave: thread b (b<16) combines its batch; lanes reduce; lane 0 writes.
__global__ __launch_bounds__(64) void bpr_finalize(
    const float* __restrict__ s_acc,
    const int*   __restrict__ cnt,
    float*       __restrict__ out)
{
    const int tid = threadIdx.x;
    float pg = 0.0f;
    if (tid < B_) {
        const int b = tid;
        float msum = 0.0f, vsum = 0.0f;
        int below = cnt[b * 4 + 0];
        #pragma unroll
        for (int lvl = 1; lvl < 4; ++lvl) {
            const int pos = cnt[b * 4 + lvl];
            const float c = (float)pos * (float)below;
            if (c > 0.0f) {
                msum += s_acc[b * 3 + (lvl - 1)] / c;
                vsum += 1.0f;
            }
            below += pos;
        }
        pg = msum / fmaxf(vsum, 1.0f);
    }
    #pragma unroll
    for (int off = 8; off > 0; off >>= 1) pg += __shfl_xor(pg, off);
    if (tid == 0) out[0] = -pg / (float)B_;
}

extern "C" void kernel_launch(void* const* d_in, const int* in_sizes, int n_in,
                              void* d_out, int out_size, void* d_ws, size_t ws_size,
                              hipStream_t stream)
{
    const float* logits = (const float*)d_in[0];
    const int*   labels = (const int*)d_in[1];
    float*       out    = (float*)d_out;
    float*       s_acc  = (float*)d_ws;
    int*         cnt    = (int*)((char*)d_ws + B_ * 3 * sizeof(float));

    // d_ws is poisoned (0xAA) and never re-poisoned between replays: zero the
    // 48 accumulators every launch (cnt is fully overwritten, no memset needed).
    (void)hipMemsetAsync(s_acc, 0, B_ * 3 * sizeof(float), stream);

    bpr_pair_kernel<<<dim3(B_ * (N_ / ITILE)), 256, 0, stream>>>(logits, labels, s_acc, cnt);
    bpr_finalize<<<1, 64, 0, stream>>>(s_acc, cnt, out);
}

// Round 5
// 22.718 us; speedup vs baseline: 10.2177x; 1.6334x over previous
//
#include <hip/hip_runtime.h>

#define B_ 16
#define N_ 2048
#define ITILE 32
#define NBLK (N_ / ITILE)          // 64 blocks per batch
#define NBLOCKS (B_ * NBLK)        // 1024 total
#define JSPLIT 8
#define JCHUNK (N_ / JSPLIT)       // 256 j-iterations per thread

// HW transcendentals: v_exp_f32 (2^x) and v_log_f32 (log2 x), single instr each.
__device__ __forceinline__ float fast_exp2(float x) { return __builtin_amdgcn_exp2f(x); }
__device__ __forceinline__ float fast_log2(float x) { return __builtin_amdgcn_logf(x); }

// ws layout (all deterministically overwritten every launch -> no memset):
//   float partials[6][NBLOCKS]   f=0..2: lgsum per level, f=3..5: ysum per level
//   int   cnt[B_][4]             label histogram (written by itile==0 blocks)

// ln sigmoid(xi - xj) = ln2 * (yi - log2(2^yi + 2^yj)),  y = x*log2(e), a = 2^y.
// Per (b,lvl): S = ln2 * (Ysum_lvl * below_lvl - LGsum_lvl); mean = S/(pos*below).

__global__ __launch_bounds__(256) void bpr_pair_kernel(
    const float* __restrict__ logits,
    const int*   __restrict__ labels,
    float*       __restrict__ partials,   // [6][NBLOCKS]
    int*         __restrict__ cnt)        // [B_][4]
{
    __shared__ float2 s_pk[N_];   // {a_j = 2^yj, (float)label_j} -> one ds_read_b64
    __shared__ float  s_y[N_];    // yj
    __shared__ float  lsum[6];    // lgsum[3], ysum[3]
    __shared__ int    wsum[8];

    const int b     = blockIdx.x / NBLK;
    const int itile = blockIdx.x % NBLK;
    const int tid   = threadIdx.x;

    const float LOG2E = 1.442695040888963f;

    // Stage row: precompute y and a once per element.
    const float* xrow = logits + (size_t)b * N_;
    const int*   lrow = labels + (size_t)b * N_;
    for (int k = tid; k < N_; k += 256) {
        const float y = xrow[k] * LOG2E;
        s_y[k]  = y;
        s_pk[k] = make_float2(fast_exp2(y), (float)lrow[k]);
    }
    if (tid < 6) lsum[tid] = 0.0f;
    __syncthreads();

    // One block per batch computes the label histogram (hidden under pair work).
    if (itile == 0) {
        int cA = 0, cB = 0;   // c0 + (c1<<16), c2 + (c3<<16)
        for (int k = tid; k < N_; k += 256) {
            const int l = (int)s_pk[k].y;
            cA += (l == 0 ? 1 : 0) + (l == 1 ? (1 << 16) : 0);
            cB += (l == 2 ? 1 : 0) + (l == 3 ? (1 << 16) : 0);
        }
        #pragma unroll
        for (int off = 32; off > 0; off >>= 1) {
            cA += __shfl_xor(cA, off);
            cB += __shfl_xor(cB, off);
        }
        if ((tid & 63) == 0) {
            wsum[(tid >> 6) * 2 + 0] = cA;
            wsum[(tid >> 6) * 2 + 1] = cB;
        }
        __syncthreads();
        if (tid == 0) {
            int tA = wsum[0] + wsum[2] + wsum[4] + wsum[6];
            int tB = wsum[1] + wsum[3] + wsum[5] + wsum[7];
            cnt[b * 4 + 0] = tA & 0xFFFF;
            cnt[b * 4 + 1] = tA >> 16;
            cnt[b * 4 + 2] = tB & 0xFFFF;
            cnt[b * 4 + 3] = tB >> 16;
        }
    }

    const int i_local = tid >> 3;   // 0..31
    const int jc      = tid & 7;    // 0..7
    const int i       = itile * ITILE + i_local;
    const float ai  = s_pk[i].x;
    const float lif = s_pk[i].y;
    const float yi  = s_y[i];
    const int   li  = (int)lif;

    // j = jc, jc+8, ... : wave touches 8 consecutive float2 slots per iter,
    // each broadcast to 8 lanes -> conflict-free. One log2 per pair.
    float acc = 0.0f;
    #pragma unroll 8
    for (int jj = 0; jj < JCHUNK; ++jj) {
        const int    j = jj * JSPLIT + jc;
        const float2 p = s_pk[j];
        const float lg = fast_log2(ai + p.x);
        acc += (p.y < lif) ? lg : 0.0f;
    }

    if (li > 0) {
        atomicAdd(&lsum[li - 1], acc);
        if (jc == 0) atomicAdd(&lsum[3 + li - 1], yi);   // each i counted once
    }
    __syncthreads();
    if (tid < 6) partials[tid * NBLOCKS + blockIdx.x] = lsum[tid];
}

// One block, 16 waves: wave b reduces its batch's 64 block-partials (coalesced).
__global__ __launch_bounds__(1024) void bpr_finalize(
    const float* __restrict__ partials,
    const int*   __restrict__ cnt,
    float*       __restrict__ out)
{
    __shared__ float pg_s[B_];
    const int tid  = threadIdx.x;
    const int b    = tid >> 6;       // wave index == batch
    const int lane = tid & 63;
    const int blk  = b * NBLK + lane;

    float v[6];
    #pragma unroll
    for (int f = 0; f < 6; ++f) v[f] = partials[f * NBLOCKS + blk];
    #pragma unroll
    for (int off = 32; off > 0; off >>= 1) {
        #pragma unroll
        for (int f = 0; f < 6; ++f) v[f] += __shfl_xor(v[f], off);
    }

    if (lane == 0) {
        const float LN2 = 0.693147180559945f;
        float msum = 0.0f, vsum = 0.0f;
        int below = cnt[b * 4 + 0];
        #pragma unroll
        for (int lvl = 1; lvl < 4; ++lvl) {
            const int pos = cnt[b * 4 + lvl];
            const float c = (float)pos * (float)below;
            if (c > 0.0f) {
                const float S = LN2 * (v[3 + lvl - 1] * (float)below - v[lvl - 1]);
                msum += S / c;
                vsum += 1.0f;
            }
            below += pos;
        }
        pg_s[b] = msum / fmaxf(vsum, 1.0f);
    }
    __syncthreads();
    if (tid == 0) {
        float total = 0.0f;
        #pragma unroll
        for (int k = 0; k < B_; ++k) total += pg_s[k];
        out[0] = -total / (float)B_;
    }
}

extern "C" void kernel_launch(void* const* d_in, const int* in_sizes, int n_in,
                              void* d_out, int out_size, void* d_ws, size_t ws_size,
                              hipStream_t stream)
{
    const float* logits   = (const float*)d_in[0];
    const int*   labels   = (const int*)d_in[1];
    float*       out      = (float*)d_out;
    float*       partials = (float*)d_ws;
    int*         cnt      = (int*)((char*)d_ws + 6 * NBLOCKS * sizeof(float));

    // No memset: every ws slot used is overwritten every launch.
    bpr_pair_kernel<<<dim3(NBLOCKS), 256, 0, stream>>>(logits, labels, partials, cnt);
    bpr_finalize<<<1, 1024, 0, stream>>>(partials, cnt, out);
}

// Round 6
// 18.763 us; speedup vs baseline: 12.3713x; 1.2108x over previous
//
#include <hip/hip_runtime.h>

#define B_ 16
#define N_ 2048
#define ITILE 32
#define NBLK (N_ / ITILE)          // 64 blocks per batch
#define NBLOCKS (B_ * NBLK)        // 1024 total

// HW transcendentals: v_exp_f32 (2^x) and v_log_f32 (log2 x), single instr each.
__device__ __forceinline__ float fast_exp2(float x) { return __builtin_amdgcn_exp2f(x); }
__device__ __forceinline__ float fast_log2(float x) { return __builtin_amdgcn_logf(x); }

// ln sigmoid(xi - xj) = ln2 * (yi - log2(2^yi + 2^yj)),  y = x*log2(e), a = 2^y.
// Per (b,lvl): S = ln2 * (Ysum_lvl * below_lvl - LGsum_lvl); mean = S/(pos*below).
//
// ws layout (all deterministically overwritten every launch -> no memset):
//   float partials[3][NBLOCKS]   per-block lgsum per level
//   float yw[B_][3]              per-batch y-sums   (itile==0 blocks)
//   int   cnt[B_][4]             label histogram    (itile==0 blocks)

__global__ __launch_bounds__(256) void bpr_pair_kernel(
    const float* __restrict__ logits,
    const int*   __restrict__ labels,
    float*       __restrict__ partials,
    float*       __restrict__ yw,
    int*         __restrict__ cnt)
{
    __shared__ float    s_a[N_];          // label-sorted a = 2^y
    __shared__ unsigned s_sc01[256];      // scan: c0 | c1<<16
    __shared__ unsigned s_sc23[256];      // scan: c2 | c3<<16
    __shared__ float    lsum[3];
    __shared__ float    wred[12];         // 4 waves x 3 y-sums

    const int b     = blockIdx.x / NBLK;
    const int itile = blockIdx.x % NBLK;
    const int tid   = threadIdx.x;
    const float LOG2E = 1.442695040888963f;

    // ---- load 8 elements/thread into registers (vectorized, coalesced) ----
    const float4* x4 = (const float4*)(logits + (size_t)b * N_);
    const int4*   l4 = (const int4*)(labels + (size_t)b * N_);
    const float4 xa = x4[tid], xb = x4[tid + 256];
    const int4   la = l4[tid], lb = l4[tid + 256];
    float xr[8]; int lr[8];
    xr[0]=xa.x; xr[1]=xa.y; xr[2]=xa.z; xr[3]=xa.w;
    xr[4]=xb.x; xr[5]=xb.y; xr[6]=xb.z; xr[7]=xb.w;
    lr[0]=la.x; lr[1]=la.y; lr[2]=la.z; lr[3]=la.w;
    lr[4]=lb.x; lr[5]=lb.y; lr[6]=lb.z; lr[7]=lb.w;

    if (tid < 3) lsum[tid] = 0.0f;

    // ---- per-thread 4-bin counts + masked y-sums ----
    int c0=0,c1=0,c2=0,c3=0;
    float y[8];
    float s1=0.0f, s2=0.0f, s3=0.0f;
    #pragma unroll
    for (int r = 0; r < 8; ++r) {
        y[r] = xr[r] * LOG2E;
        c0 += (lr[r]==0); c1 += (lr[r]==1); c2 += (lr[r]==2); c3 += (lr[r]==3);
        s1 += (lr[r]==1) ? y[r] : 0.0f;
        s2 += (lr[r]==2) ? y[r] : 0.0f;
        s3 += (lr[r]==3) ? y[r] : 0.0f;
    }

    // ---- block-wide inclusive scan of packed counts (16-bit fields) ----
    unsigned v01 = (unsigned)c0 | ((unsigned)c1 << 16);
    unsigned v23 = (unsigned)c2 | ((unsigned)c3 << 16);
    s_sc01[tid] = v01; s_sc23[tid] = v23;
    __syncthreads();
    #pragma unroll
    for (int off = 1; off < 256; off <<= 1) {
        unsigned a01 = v01, a23 = v23;
        if (tid >= off) { a01 += s_sc01[tid - off]; a23 += s_sc23[tid - off]; }
        __syncthreads();
        s_sc01[tid] = a01; s_sc23[tid] = a23;
        v01 = a01; v23 = a23;
        __syncthreads();
    }
    const unsigned t01 = s_sc01[255], t23 = s_sc23[255];
    const int tot0 = (int)(t01 & 0xFFFFu), tot1 = (int)(t01 >> 16);
    const int tot2 = (int)(t23 & 0xFFFFu), tot3 = (int)(t23 >> 16);
    const int base1 = tot0, base2 = tot0 + tot1, base3 = tot0 + tot1 + tot2;

    // per-thread scatter cursors (exclusive prefix + bucket base)
    int o0 = (int)(v01 & 0xFFFFu) - c0;
    int o1 = base1 + ((int)(v01 >> 16) - c1);
    int o2 = base2 + ((int)(v23 & 0xFFFFu) - c2);
    int o3 = base3 + ((int)(v23 >> 16) - c3);

    // ---- y-sum wave reduce (all blocks compute; only itile==0 writes) ----
    #pragma unroll
    for (int off = 32; off > 0; off >>= 1) {
        s1 += __shfl_xor(s1, off);
        s2 += __shfl_xor(s2, off);
        s3 += __shfl_xor(s3, off);
    }
    if ((tid & 63) == 0) {
        const int w = tid >> 6;
        wred[w*3+0] = s1; wred[w*3+1] = s2; wred[w*3+2] = s3;
    }

    // ---- scatter a = 2^y into label-sorted LDS ----
    #pragma unroll
    for (int r = 0; r < 8; ++r) {
        const int l = lr[r];
        const int slot = (l==0) ? o0 : (l==1) ? o1 : (l==2) ? o2 : o3;
        o0 += (l==0); o1 += (l==1); o2 += (l==2); o3 += (l==3);
        s_a[slot] = fast_exp2(y[r]);
    }
    __syncthreads();

    if (itile == 0 && tid == 0) {
        cnt[b*4+0]=tot0; cnt[b*4+1]=tot1; cnt[b*4+2]=tot2; cnt[b*4+3]=tot3;
        yw[b*3+0] = wred[0]+wred[3]+wred[6]+wred[9];
        yw[b*3+1] = wred[1]+wred[4]+wred[7]+wred[10];
        yw[b*3+2] = wred[2]+wred[5]+wred[8]+wred[11];
    }

    // ---- pair loop over sorted prefix only (no mask, 1 log2 per 4 pairs) ----
    const int i  = itile * ITILE + (tid >> 3);
    const int jc = tid & 7;
    const float ai = s_a[i];
    const int li    = (i >= base1) + (i >= base2) + (i >= base3);
    const int below = (li==0) ? 0 : (li==1) ? base1 : (li==2) ? base2 : base3;

    const int nit = (below > jc) ? ((below - jc + 7) >> 3) : 0;
    const int n4  = nit >> 2;
    const int rem = nit & 3;

    float acc = 0.0f;
    int j = jc;
    for (int g = 0; g < n4; ++g) {
        const float t0 = ai + s_a[j];
        const float t1 = ai + s_a[j + 8];
        const float t2 = ai + s_a[j + 16];
        const float t3 = ai + s_a[j + 24];
        acc += fast_log2((t0 * t1) * (t2 * t3));
        j += 32;
    }
    float t = 1.0f;
    for (int g = 0; g < rem; ++g) { t *= (ai + s_a[j]); j += 8; }
    acc += fast_log2(t);   // log2(1) == 0 exactly when rem == 0

    if (li > 0) atomicAdd(&lsum[li - 1], acc);
    __syncthreads();
    if (tid < 3) partials[tid * NBLOCKS + blockIdx.x] = lsum[tid];
}

// One block, 16 waves: wave b reduces its batch's 64 block-partials (coalesced).
__global__ __launch_bounds__(1024) void bpr_finalize(
    const float* __restrict__ partials,
    const float* __restrict__ yw,
    const int*   __restrict__ cnt,
    float*       __restrict__ out)
{
    __shared__ float pg_s[B_];
    const int tid  = threadIdx.x;
    const int b    = tid >> 6;       // wave index == batch
    const int lane = tid & 63;
    const int blk  = b * NBLK + lane;

    float v0 = partials[0 * NBLOCKS + blk];
    float v1 = partials[1 * NBLOCKS + blk];
    float v2 = partials[2 * NBLOCKS + blk];
    #pragma unroll
    for (int off = 32; off > 0; off >>= 1) {
        v0 += __shfl_xor(v0, off);
        v1 += __shfl_xor(v1, off);
        v2 += __shfl_xor(v2, off);
    }

    if (lane == 0) {
        const float LN2 = 0.693147180559945f;
        const int n0 = cnt[b*4+0], n1 = cnt[b*4+1], n2 = cnt[b*4+2], n3 = cnt[b*4+3];
        float msum = 0.0f, vsum = 0.0f;
        // lvl 1
        {
            const float c = (float)n1 * (float)n0;
            if (c > 0.0f) { msum += LN2 * (yw[b*3+0] * (float)n0 - v0) / c; vsum += 1.0f; }
        }
        // lvl 2
        {
            const int bl = n0 + n1;
            const float c = (float)n2 * (float)bl;
            if (c > 0.0f) { msum += LN2 * (yw[b*3+1] * (float)bl - v1) / c; vsum += 1.0f; }
        }
        // lvl 3
        {
            const int bl = n0 + n1 + n2;
            const float c = (float)n3 * (float)bl;
            if (c > 0.0f) { msum += LN2 * (yw[b*3+2] * (float)bl - v2) / c; vsum += 1.0f; }
        }
        pg_s[b] = msum / fmaxf(vsum, 1.0f);
    }
    __syncthreads();
    if (tid == 0) {
        float total = 0.0f;
        #pragma unroll
        for (int k = 0; k < B_; ++k) total += pg_s[k];
        out[0] = -total / (float)B_;
    }
}

extern "C" void kernel_launch(void* const* d_in, const int* in_sizes, int n_in,
                              void* d_out, int out_size, void* d_ws, size_t ws_size,
                              hipStream_t stream)
{
    const float* logits   = (const float*)d_in[0];
    const int*   labels   = (const int*)d_in[1];
    float*       out      = (float*)d_out;
    float*       partials = (float*)d_ws;
    float*       ywp      = (float*)((char*)d_ws + 3 * NBLOCKS * sizeof(float));
    int*         cntp     = (int*)((char*)d_ws + (3 * NBLOCKS + 3 * B_) * sizeof(float));

    // No memset: every ws slot used is overwritten every launch.
    bpr_pair_kernel<<<dim3(NBLOCKS), 256, 0, stream>>>(logits, labels, partials, ywp, cntp);
    bpr_finalize<<<1, 1024, 0, stream>>>(partials, ywp, cntp, out);
}

// Round 7
// 14.851 us; speedup vs baseline: 15.6304x; 1.2634x over previous
//
#include <hip/hip_runtime.h>

#define B_ 16
#define N_ 2048
#define ITILE 64                   // rows per block, 2 per thread
#define NBLK (N_ / ITILE)          // 32 blocks per batch
#define NBLOCKS (B_ * NBLK)        // 512 total

// HW transcendentals: v_exp_f32 (2^x) and v_log_f32 (log2 x), single instr each.
__device__ __forceinline__ float fast_exp2(float x) { return __builtin_amdgcn_exp2f(x); }
__device__ __forceinline__ float fast_log2(float x) { return __builtin_amdgcn_logf(x); }

// ln sigmoid(xi - xj) = ln2 * (yi - log2(2^yi + 2^yj)),  y = x*log2(e), a = 2^y.
// Per (b,lvl): S = ln2 * (Ysum_lvl * below_lvl - LGsum_lvl); mean = S/(pos*below).
//
// ws layout (all deterministically overwritten every launch -> no memset):
//   float partials[3][NBLOCKS]; float yw[B_][3]; int cnt[B_][4]

__global__ __launch_bounds__(256) void bpr_pair_kernel(
    const float* __restrict__ logits,
    const int*   __restrict__ labels,
    float*       __restrict__ partials,
    float*       __restrict__ yw,
    int*         __restrict__ cnt)
{
    __shared__ float    s_a[N_];       // label-sorted a = 2^y
    __shared__ unsigned wtot01[4], wtot23[4];
    __shared__ float    wred[4][3];    // per-wave level sums
    __shared__ float    yred[4][3];    // per-wave y sums

    const int b     = blockIdx.x / NBLK;
    const int itile = blockIdx.x % NBLK;
    const int tid   = threadIdx.x;
    const int lane  = tid & 63;
    const int w     = tid >> 6;
    const float LOG2E = 1.442695040888963f;

    // ---- load 8 elements/thread (vectorized, coalesced) ----
    const float4* x4 = (const float4*)(logits + (size_t)b * N_);
    const int4*   l4 = (const int4*)(labels + (size_t)b * N_);
    const float4 xa = x4[tid], xb = x4[tid + 256];
    const int4   la = l4[tid], lb = l4[tid + 256];
    float y[8]; int lr[8];
    y[0]=xa.x*LOG2E; y[1]=xa.y*LOG2E; y[2]=xa.z*LOG2E; y[3]=xa.w*LOG2E;
    y[4]=xb.x*LOG2E; y[5]=xb.y*LOG2E; y[6]=xb.z*LOG2E; y[7]=xb.w*LOG2E;
    lr[0]=la.x; lr[1]=la.y; lr[2]=la.z; lr[3]=la.w;
    lr[4]=lb.x; lr[5]=lb.y; lr[6]=lb.z; lr[7]=lb.w;

    // ---- per-thread 4-bin counts + masked y-sums ----
    int c0=0,c1=0,c2=0,c3=0;
    float s1=0.0f, s2=0.0f, s3=0.0f;
    #pragma unroll
    for (int r = 0; r < 8; ++r) {
        c0 += (lr[r]==0); c1 += (lr[r]==1); c2 += (lr[r]==2); c3 += (lr[r]==3);
        s1 += (lr[r]==1) ? y[r] : 0.0f;
        s2 += (lr[r]==2) ? y[r] : 0.0f;
        s3 += (lr[r]==3) ? y[r] : 0.0f;
    }

    // ---- wave-level inclusive scan of packed counts (no barriers) ----
    const unsigned v01 = (unsigned)c0 | ((unsigned)c1 << 16);
    const unsigned v23 = (unsigned)c2 | ((unsigned)c3 << 16);
    unsigned i01 = v01, i23 = v23;
    #pragma unroll
    for (int off = 1; off < 64; off <<= 1) {
        const unsigned t01 = __shfl_up(i01, off);
        const unsigned t23 = __shfl_up(i23, off);
        if (lane >= off) { i01 += t01; i23 += t23; }
    }
    if (lane == 63) { wtot01[w] = i01; wtot23[w] = i23; }

    // y-sum wave reduce (cheap; only itile==0 block's result is used)
    float r1=s1, r2=s2, r3=s3;
    #pragma unroll
    for (int off = 32; off > 0; off >>= 1) {
        r1 += __shfl_xor(r1, off); r2 += __shfl_xor(r2, off); r3 += __shfl_xor(r3, off);
    }
    if (lane == 0) { yred[w][0]=r1; yred[w][1]=r2; yred[w][2]=r3; }
    __syncthreads();                               // barrier 1: wtot/yred ready

    unsigned p01 = 0, p23 = 0, g01 = 0, g23 = 0;
    #pragma unroll
    for (int k = 0; k < 4; ++k) {
        if (k < w) { p01 += wtot01[k]; p23 += wtot23[k]; }
        g01 += wtot01[k]; g23 += wtot23[k];
    }
    const int tot0 = (int)(g01 & 0xFFFFu), tot1 = (int)(g01 >> 16);
    const int tot2 = (int)(g23 & 0xFFFFu), tot3 = (int)(g23 >> 16);
    const int base1 = tot0, base2 = tot0 + tot1, base3 = tot0 + tot1 + tot2;

    const unsigned e01 = p01 + i01 - v01, e23 = p23 + i23 - v23;
    int o0 = (int)(e01 & 0xFFFFu);
    int o1 = base1 + (int)(e01 >> 16);
    int o2 = base2 + (int)(e23 & 0xFFFFu);
    int o3 = base3 + (int)(e23 >> 16);

    // ---- scatter a = 2^y into label-sorted LDS ----
    #pragma unroll
    for (int r = 0; r < 8; ++r) {
        const int l = lr[r];
        const int slot = (l==0) ? o0 : (l==1) ? o1 : (l==2) ? o2 : o3;
        o0 += (l==0); o1 += (l==1); o2 += (l==2); o3 += (l==3);
        s_a[slot] = fast_exp2(y[r]);
    }
    __syncthreads();                               // barrier 2: s_a ready

    if (itile == 0 && tid == 0) {
        cnt[b*4+0]=tot0; cnt[b*4+1]=tot1; cnt[b*4+2]=tot2; cnt[b*4+3]=tot3;
        yw[b*3+0] = yred[0][0]+yred[1][0]+yred[2][0]+yred[3][0];
        yw[b*3+1] = yred[0][1]+yred[1][1]+yred[2][1]+yred[3][1];
        yw[b*3+2] = yred[0][2]+yred[1][2]+yred[2][2]+yred[3][2];
    }

    // ---- pair loop: 2 rows/thread, b128 j-reads, 8-term log amortization ----
    const int rg = tid >> 3, jc = tid & 7;
    const int i0 = itile * ITILE + rg * 2, i1 = i0 + 1;
    const float ai0 = s_a[i0], ai1 = s_a[i1];
    const int li0 = (i0>=base1)+(i0>=base2)+(i0>=base3);
    const int li1 = (i1>=base1)+(i1>=base2)+(i1>=base3);
    const int bl0 = (li0==0)?0:(li0==1)?base1:(li0==2)?base2:base3;
    const int bl1 = (li1==0)?0:(li1==1)?base1:(li1==2)?base2:base3;
    const int blmin = min(bl0, bl1), blmax = max(bl0, bl1);

    const int j0 = jc * 4;
    const int ng  = (blmax > j0) ? ((blmax - j0 + 31) >> 5) : 0;
    const int ngf = (blmin >= j0 + 4) ? (((blmin - j0 - 4) >> 5) + 1) : 0;

    float acc0 = 0.0f, acc1 = 0.0f;
    float pr0 = 1.0f, pr1 = 1.0f;
    int j = j0, g = 0;
    for (; g < ngf; ++g) {                         // fully-valid groups: no masks
        const float4 aj = *(const float4*)&s_a[j];
        pr0 *= ((ai0+aj.x)*(ai0+aj.y)) * ((ai0+aj.z)*(ai0+aj.w));
        pr1 *= ((ai1+aj.x)*(ai1+aj.y)) * ((ai1+aj.z)*(ai1+aj.w));
        if (g & 1) { acc0 += fast_log2(pr0); pr0 = 1.0f;
                     acc1 += fast_log2(pr1); pr1 = 1.0f; }
        j += 32;
    }
    for (; g < ng; ++g) {                          // <=2 boundary groups: masked
        const float4 aj = *(const float4*)&s_a[j];
        pr0 *= (j+0<bl0 ? ai0+aj.x : 1.0f) * (j+1<bl0 ? ai0+aj.y : 1.0f)
             * (j+2<bl0 ? ai0+aj.z : 1.0f) * (j+3<bl0 ? ai0+aj.w : 1.0f);
        pr1 *= (j+0<bl1 ? ai1+aj.x : 1.0f) * (j+1<bl1 ? ai1+aj.y : 1.0f)
             * (j+2<bl1 ? ai1+aj.z : 1.0f) * (j+3<bl1 ? ai1+aj.w : 1.0f);
        if (g & 1) { acc0 += fast_log2(pr0); pr0 = 1.0f;
                     acc1 += fast_log2(pr1); pr1 = 1.0f; }
        j += 32;
    }
    acc0 += fast_log2(pr0);                        // flush (log2(1)==0)
    acc1 += fast_log2(pr1);

    // ---- register level-accumulate (no atomics) + block reduce ----
    float aL0 = ((li0==1)?acc0:0.0f) + ((li1==1)?acc1:0.0f);
    float aL1 = ((li0==2)?acc0:0.0f) + ((li1==2)?acc1:0.0f);
    float aL2 = ((li0==3)?acc0:0.0f) + ((li1==3)?acc1:0.0f);
    #pragma unroll
    for (int off = 32; off > 0; off >>= 1) {
        aL0 += __shfl_xor(aL0, off); aL1 += __shfl_xor(aL1, off); aL2 += __shfl_xor(aL2, off);
    }
    if (lane == 0) { wred[w][0]=aL0; wred[w][1]=aL1; wred[w][2]=aL2; }
    __syncthreads();                               // barrier 3
    if (tid < 3)
        partials[tid * NBLOCKS + blockIdx.x] =
            wred[0][tid] + wred[1][tid] + wred[2][tid] + wred[3][tid];
}

// One block, 512 threads: 32 lanes per batch reduce its 32 block-partials.
__global__ __launch_bounds__(512) void bpr_finalize(
    const float* __restrict__ partials,
    const float* __restrict__ yw,
    const int*   __restrict__ cnt,
    float*       __restrict__ out)
{
    __shared__ float pg_s[B_];
    const int tid = threadIdx.x;

    float v0 = partials[0 * NBLOCKS + tid];
    float v1 = partials[1 * NBLOCKS + tid];
    float v2 = partials[2 * NBLOCKS + tid];
    #pragma unroll
    for (int off = 16; off > 0; off >>= 1) {       // reduce within 32-lane groups
        v0 += __shfl_xor(v0, off); v1 += __shfl_xor(v1, off); v2 += __shfl_xor(v2, off);
    }

    const int b = tid >> 5;
    if ((tid & 31) == 0) {
        const float LN2 = 0.693147180559945f;
        const int n0 = cnt[b*4+0], n1 = cnt[b*4+1], n2 = cnt[b*4+2], n3 = cnt[b*4+3];
        float msum = 0.0f, vsum = 0.0f;
        {
            const float c = (float)n1 * (float)n0;
            if (c > 0.0f) { msum += LN2 * (yw[b*3+0] * (float)n0 - v0) / c; vsum += 1.0f; }
        }
        {
            const int bl = n0 + n1;
            const float c = (float)n2 * (float)bl;
            if (c > 0.0f) { msum += LN2 * (yw[b*3+1] * (float)bl - v1) / c; vsum += 1.0f; }
        }
        {
            const int bl = n0 + n1 + n2;
            const float c = (float)n3 * (float)bl;
            if (c > 0.0f) { msum += LN2 * (yw[b*3+2] * (float)bl - v2) / c; vsum += 1.0f; }
        }
        pg_s[b] = msum / fmaxf(vsum, 1.0f);
    }
    __syncthreads();
    if (tid == 0) {
        float total = 0.0f;
        #pragma unroll
        for (int k = 0; k < B_; ++k) total += pg_s[k];
        out[0] = -total / (float)B_;
    }
}

extern "C" void kernel_launch(void* const* d_in, const int* in_sizes, int n_in,
                              void* d_out, int out_size, void* d_ws, size_t ws_size,
                              hipStream_t stream)
{
    const float* logits   = (const float*)d_in[0];
    const int*   labels   = (const int*)d_in[1];
    float*       out      = (float*)d_out;
    float*       partials = (float*)d_ws;
    float*       ywp      = (float*)((char*)d_ws + 3 * NBLOCKS * sizeof(float));
    int*         cntp     = (int*)((char*)d_ws + (3 * NBLOCKS + 3 * B_) * sizeof(float));

    // No memset: every ws slot used is overwritten every launch.
    bpr_pair_kernel<<<dim3(NBLOCKS), 256, 0, stream>>>(logits, labels, partials, ywp, cntp);
    bpr_finalize<<<1, 512, 0, stream>>>(partials, ywp, cntp, out);
}